// Round 8
// baseline (244.547 us; speedup 1.0000x reference)
//
#include <hip/hip_runtime.h>
#include <math.h>

#define Vn 5
#define Cn 32
#define Hn 384
#define Wn 384
#define Dn 4
#define Gn 8
#define HWn (Hn*Wn)   // 147456

typedef _Float16 h2 __attribute__((ext_vector_type(2)));
typedef float    f2 __attribute__((ext_vector_type(2)));

__device__ __forceinline__ float fdot2h(h2 a, h2 b, float c){
#if __has_builtin(__builtin_amdgcn_fdot2)
    return __builtin_amdgcn_fdot2(a, b, c, false);
#else
    return (float)a.x*(float)b.x + (float)a.y*(float)b.y + c;
#endif
}
__device__ __forceinline__ unsigned int packh2(float a, float b){  // accurate pack (RNE)
    h2 h;
    h.x = (_Float16)a;
    h.y = (_Float16)b;
    return __builtin_bit_cast(unsigned int, h);
}
// packed fp32 helpers -> v_pk_fma_f32 / v_pk_max_f32 (exact same fma math per lane)
__device__ __forceinline__ f2 fma2(f2 a, f2 b, f2 c){ return __builtin_elementwise_fma(a, b, c); }
__device__ __forceinline__ f2 max2(f2 a, f2 b){ return __builtin_elementwise_max(a, b); }
__device__ __forceinline__ f2 splat2(float x){ f2 r; r.x = x; r.y = x; return r; }

// ---------- small 3x3 helpers (device) ----------
__device__ __forceinline__ void inv3(const float* m, float* o){
    float a=m[0],b=m[1],c=m[2],d=m[3],e=m[4],f=m[5],g=m[6],h=m[7],i=m[8];
    float A =  e*i - f*h;
    float B = -(d*i - f*g);
    float C =  d*h - e*g;
    float det = a*A + b*B + c*C;
    float r = 1.f/det;
    o[0] = A*r;            o[1] = -(b*i - c*h)*r;  o[2] =  (b*f - c*e)*r;
    o[3] = B*r;            o[4] =  (a*i - c*g)*r;  o[5] = -(a*f - c*d)*r;
    o[6] = C*r;            o[7] = -(a*h - b*g)*r;  o[8] =  (a*e - b*d)*r;
}
__device__ __forceinline__ void mm3(const float* a, const float* b, float* o){
    #pragma unroll
    for (int r=0;r<3;r++)
        #pragma unroll
        for (int c=0;c<3;c++)
            o[r*3+c] = a[r*3+0]*b[0*3+c] + a[r*3+1]*b[1*3+c] + a[r*3+2]*b[2*3+c];
}
__device__ __forceinline__ void mv3(const float* a, const float* v, float* o){
    #pragma unroll
    for (int r=0;r<3;r++)
        o[r] = a[r*3+0]*v[0] + a[r*3+1]*v[1] + a[r*3+2]*v[2];
}

// ---------- transpose+convert (C,H,W) fp32 -> (H*W, C) f16 ----------
// R7 structure (kept): instruction-contiguous loads AND stores via LDS
// exchange; 2 px/thread, 18KB LDS, 2304 blocks. R7 post-mortem: occupancy
// doubling gave ~0 -> transpose is near its floor; "rest" is dominated by
// fixed harness overhead (~100us of reset/memset dispatches), not transpose.
__global__ __launch_bounds__(128)
void transpose_kernel(const float* __restrict__ feat, unsigned short* __restrict__ featT){
    __shared__ uint4 lds[128*9];                            // 18KB: 8 chunks + 1 pad/thread
    const int s  = blockIdx.y;                              // 0..3 -> view s+1
    const int P0 = blockIdx.x * 256;
    const int t  = threadIdx.x;
    const float* src = feat + (size_t)(s+1)*Cn*HWn + P0 + 2*t;
    unsigned int outw[2][16];
    #pragma unroll
    for (int c=0; c<Cn; c+=2){
        const f2 a = *(const f2*)(src + (size_t)c*HWn);
        const f2 b = *(const f2*)(src + (size_t)(c+1)*HWn);
        outw[0][c>>1] = packh2(a.x, b.x);
        outw[1][c>>1] = packh2(a.y, b.y);
    }
    #pragma unroll
    for (int p=0;p<2;p++)
        #pragma unroll
        for (int j=0;j<4;j++){
            uint4 o;
            o.x = outw[p][4*j+0];
            o.y = outw[p][4*j+1];
            o.z = outw[p][4*j+2];
            o.w = outw[p][4*j+3];
            lds[t*9 + p*4 + j] = o;
        }
    __syncthreads();
    unsigned short* dstb = featT + ((size_t)s*HWn + P0)*Cn;
    #pragma unroll
    for (int k=0;k<8;k++){
        const int c = k*128 + t;
        const uint4 v = lds[(c>>3)*9 + (c&7)];
        *(uint4*)(dstb + (size_t)c*8) = v;
    }
}

// one group (4 ch = 2 half2): two v_dot2_f32_f16 + one fma into sg[g]
#define DOTG(uA, uB, g, WV)                                                    \
    {                                                                          \
        const h2 pa = __builtin_bit_cast(h2, (uA));                            \
        const h2 pb = __builtin_bit_cast(h2, (uB));                            \
        const float dt = fdot2h(pa, r2[2*(g)], fdot2h(pb, r2[2*(g)+1], 0.f));  \
        sg[(g)] = fmaf((WV), dt, sg[(g)]);                                     \
    }

// R8: BRANCHLESS tap. The w!=0 guards were exec-mask branch boundaries that
// pinned the schedule to 1 gather in flight per wave (guards are ~always
// true for interior pixels anyway). Removing them lets the scheduler hoist
// the next tap's load over the current dot chain (~2 records in flight).
// Numerics bit-identical: clamped coords are always-safe loads, and
// fmaf(0, dt, sg) == sg exactly (records are finite f16).
// R2 cliff guard: __launch_bounds__(256,3) caps VGPR ~85 so the compiler
// CANNOT recreate the 16-record batch (which needed 128 VGPR and lost 65%).
__device__ __forceinline__ void tap_f16(const unsigned short* __restrict__ vbase,
                                        int xc, int yc, float w,
                                        const h2* r2, float* sg)
{
    const uint4* p = (const uint4*)(vbase + ((size_t)yc*Wn + xc)*Cn);
    const uint4 q0 = p[0];
    const uint4 q1 = p[1];
    const uint4 q2 = p[2];
    const uint4 q3 = p[3];
    DOTG(q0.x, q0.y, 0, w)
    DOTG(q0.z, q0.w, 1, w)
    DOTG(q1.x, q1.y, 2, w)
    DOTG(q1.z, q1.w, 3, w)
    DOTG(q2.x, q2.y, 4, w)
    DOTG(q2.z, q2.w, 5, w)
    DOTG(q3.x, q3.y, 6, w)
    DOTG(q3.z, q3.w, 7, w)
}

// ---------- fused main kernel (R4 structure; R8 = branchless taps) ----------
// One thread per (pixel, view, depth-half). Block = 256 threads =
// 32 pixels x 8 lanes; lane sub = s*2 + h. Each thread: 2 depths x 4 taps,
// packed-f2 MLP pass, shfl_xor(1) folds depth-half maxlog, shfl_xor(2)/(4)
// view reduction. NOTE: register arrays only with compile-time indices (SROA).
__global__ __launch_bounds__(256, 3)
void gbinet_kernel(const float* __restrict__ feat,
                   const float* __restrict__ depths,
                   const float* __restrict__ Kin,
                   const float* __restrict__ Ein,
                   const float* __restrict__ w0, const float* __restrict__ b0,
                   const float* __restrict__ w1, const float* __restrict__ b1,
                   const float* __restrict__ w2, const float* __restrict__ b2,
                   const unsigned short* __restrict__ featT,
                   float* __restrict__ out)
{
    __shared__ float sW0[128], sW1[128], sB0[16], sB1[8], sW2[8], sB2s[1];
    __shared__ float sM[48];            // per source view: A[9] + c[3]
    __shared__ float sRef[32*33];       // 32 pixels x 32 ref channels (pad 33)
    __shared__ float sDep[4*33];        // 4 depth planes x 32 pixels (pad 33)
    __shared__ float sOut[32*33];       // 32 pixels x 32 outputs (pad 33)
    const int t = threadIdx.x;
    if (t < 128){ sW0[t] = w0[t]; sW1[t] = w1[t]; }
    if (t < 16) sB0[t] = b0[t];
    if (t < 8){ sB1[t] = b1[t]; sW2[t] = w2[t]; }

    // XCD swizzle: round-robin dispatch -> each XCD gets a contiguous
    // 576-block (48-row) strip; featT tap neighborhoods stay in its L2.
    const int bid = blockIdx.x;
    const int sid = (bid & 7) * (HWn/32/8) + (bid >> 3);
    const int blockBase = sid * 32;

    // cooperative coalesced stage of ref (view0 fp32) and depths for 32 pixels
    {
        const float* srcR = feat + blockBase;
        #pragma unroll
        for (int k=0;k<4;k++){
            const int i  = k*256 + t;
            const int c  = i >> 5;
            const int px = i & 31;
            sRef[px*33 + c] = srcR[(size_t)c*HWn + px];
        }
        if (t < 128){
            const int dp = t >> 5;      // 0..3
            const int px = t & 31;
            sDep[dp*33 + px] = depths[(size_t)dp*HWn + blockBase + px];
        }
    }

    // Projection-chain setup, 4-way lane-parallel (one lane per source view).
    if (t < 4){
        float K0inv[9]; inv3(Kin, K0inv);
        float R0[9], t0[3];
        #pragma unroll
        for (int r=0;r<3;r++){
            #pragma unroll
            for (int c=0;c<3;c++) R0[r*3+c] = Ein[r*4+c];
            t0[r] = Ein[r*4+3];
        }
        float R0inv[9]; inv3(R0, R0inv);
        float M0[9]; mm3(R0inv, K0inv, M0);
        float Rt0[3]; mv3(R0inv, t0, Rt0);
        const int sv = t + 1;
        const float* Ks = Kin + sv*9;
        const float* Es = Ein + sv*12;
        float Rs[9], ts[3];
        #pragma unroll
        for (int r=0;r<3;r++){
            #pragma unroll
            for (int c=0;c<3;c++) Rs[r*3+c] = Es[r*4+c];
            ts[r] = Es[r*4+3];
        }
        float T1[9]; mm3(Rs, M0, T1);
        float A[9];  mm3(Ks, T1, A);
        float Rr[3]; mv3(Rs, Rt0, Rr);
        float tv[3] = { ts[0]-Rr[0], ts[1]-Rr[1], ts[2]-Rr[2] };
        float cv[3]; mv3(Ks, tv, cv);
        float* dm = &sM[t*12];
        #pragma unroll
        for (int i=0;i<9;i++) dm[i] = A[i];
        #pragma unroll
        for (int i=0;i<3;i++) dm[9+i] = cv[i];
    }
    if (t == 4) sB2s[0] = b2[0];
    __syncthreads();

    const int pixLocal = t >> 3;        // 0..31
    const int sub      = t & 7;
    const int s        = sub >> 1;      // source view index (0..3 -> view s+1)
    const int hh       = sub & 1;       // depth-half: depths {2h, 2h+1}
    const int pix      = blockBase + pixLocal;
    const float xg = (float)(pix % Wn) + 0.5f;
    const float yg = (float)(pix / Wn) + 0.5f;

    // ref as 16 packed half2 (f16 precision > bf16 for N(0,1) data)
    h2 r2[16];
    #pragma unroll
    for (int k=0;k<16;k++){
        r2[k].x = (_Float16)sRef[pixLocal*33 + 2*k];
        r2[k].y = (_Float16)sRef[pixLocal*33 + 2*k+1];
    }
    float dep[2];
    #pragma unroll
    for (int d=0;d<2;d++) dep[d] = sDep[(2*hh + d)*33 + pixLocal];

    const float* M = &sM[s*12];
    const float bx = M[0]*xg + M[1]*yg + M[2];
    const float by = M[3]*xg + M[4]*yg + M[5];
    const float bz = M[6]*xg + M[7]*yg + M[8];
    const float cx = M[9], cy = M[10], cz = M[11];
    const unsigned short* vbase = featT + (size_t)s*HWn*Cn;

    float sim[Gn][2];
    #pragma unroll
    for (int d=0;d<2;d++){
        const float dd = dep[d];
        const float ux = fmaf(bx, dd, cx);
        const float uy = fmaf(by, dd, cy);
        const float uz = fmaf(bz, dd, cz) + 1e-9f;
        const float rz = 1.f/uz;
        const float px = ux*rz, py = uy*rz;
        const float x0 = floorf(px), y0 = floorf(py);
        const float wx1 = px - x0, wy1 = py - y0;
        const float wx0 = 1.f - wx1, wy0 = 1.f - wy1;
        const bool vx0 = (x0 >= 0.f)     && (x0 <= (float)(Wn-1));
        const bool vx1 = (x0 >= -1.f)    && (x0 <= (float)(Wn-2));
        const bool vy0 = (y0 >= 0.f)     && (y0 <= (float)(Hn-1));
        const bool vy1 = (y0 >= -1.f)    && (y0 <= (float)(Hn-2));
        // fold the 1/4 group-mean into the tap weights
        const float w00 = (vx0&&vy0) ? 0.25f*wx0*wy0 : 0.f;
        const float w10 = (vx1&&vy0) ? 0.25f*wx1*wy0 : 0.f;
        const float w01 = (vx0&&vy1) ? 0.25f*wx0*wy1 : 0.f;
        const float w11 = (vx1&&vy1) ? 0.25f*wx1*wy1 : 0.f;
        // clamped integer coords (always safe to load)
        const int xi0 = (int)fminf(fmaxf(x0,     0.f), (float)(Wn-1));
        const int xi1 = (int)fminf(fmaxf(x0+1.f, 0.f), (float)(Wn-1));
        const int yi0 = (int)fminf(fmaxf(y0,     0.f), (float)(Hn-1));
        const int yi1 = (int)fminf(fmaxf(y0+1.f, 0.f), (float)(Hn-1));

        float sg[Gn];
        #pragma unroll
        for (int g=0; g<Gn; g++) sg[g] = 0.f;
        tap_f16(vbase, xi0, yi0, w00, r2, sg);
        tap_f16(vbase, xi1, yi0, w10, r2, sg);
        tap_f16(vbase, xi0, yi1, w01, r2, sg);
        tap_f16(vbase, xi1, yi1, w11, r2, sg);
        #pragma unroll
        for (int g=0; g<Gn; g++) sim[g][d] = sg[g];
    }

    // pixelwise net on this lane's depth pair via packed fp32
    // (v_pk_fma_f32 / v_pk_max_f32): identical fma chain -> bit-identical.
    // max(sigmoid) == sigmoid(max logit).
    f2 sv[Gn];
    #pragma unroll
    for (int g=0; g<Gn; g++){ sv[g].x = sim[g][0]; sv[g].y = sim[g][1]; }
    f2 hreg[16];
    #pragma unroll
    for (int o=0;o<16;o++){
        f2 a = splat2(sB0[o]);
        #pragma unroll
        for (int g=0; g<Gn; g++)
            a = fma2(splat2(sW0[o*Gn+g]), sv[g], a);
        hreg[o] = max2(a, splat2(0.f));
    }
    f2 lg = splat2(sB2s[0]);
    #pragma unroll
    for (int o=0;o<8;o++){
        f2 a = splat2(sB1[o]);
        #pragma unroll
        for (int i=0;i<16;i++)
            a = fma2(splat2(sW1[o*16+i]), hreg[i], a);
        lg = fma2(splat2(sW2[o]), max2(a, splat2(0.f)), lg);
    }
    float mx = fmaxf(lg.x, lg.y);
    const float maxlog = fmaxf(mx, __shfl_xor(mx, 1));   // fold depth halves
    const float vw = 1.f/(1.f + __expf(-maxlog));

    // scale by vw, butterfly-reduce across the 4 view lanes (bits 1-2)
    float wsum = vw;
    wsum += __shfl_xor(wsum, 2);
    wsum += __shfl_xor(wsum, 4);
    #pragma unroll
    for (int g=0;g<Gn;g++)
        #pragma unroll
        for (int d=0;d<2;d++){
            float v = sim[g][d]*vw;
            v += __shfl_xor(v, 2);
            v += __shfl_xor(v, 4);
            sim[g][d] = v;
        }

    if (s == 0){                        // sub 0 (depths 0,1) and sub 1 (2,3)
        const float invw = 1.f/wsum;
        #pragma unroll
        for (int g=0;g<Gn;g++)
            #pragma unroll
            for (int d=0;d<2;d++)
                sOut[pixLocal*33 + g*Dn + 2*hh + d] = sim[g][d]*invw;
    }
    __syncthreads();

    // coalesced write-out: 32 planes x 32 pixels
    float* oBase = out + blockBase;
    #pragma unroll
    for (int k=0;k<4;k++){
        const int e     = k*256 + t;
        const int plane = e >> 5;
        const int pixel = e & 31;
        oBase[(size_t)plane*HWn + pixel] = sOut[pixel*33 + plane];
    }
}

extern "C" void kernel_launch(void* const* d_in, const int* in_sizes, int n_in,
                              void* d_out, int out_size, void* d_ws, size_t ws_size,
                              hipStream_t stream)
{
    (void)in_sizes; (void)n_in; (void)out_size; (void)ws_size;
    const float* feat   = (const float*)d_in[0];
    const float* depths = (const float*)d_in[1];
    const float* K      = (const float*)d_in[2];
    const float* E      = (const float*)d_in[3];
    const float* w0     = (const float*)d_in[4];
    const float* b0     = (const float*)d_in[5];
    const float* w1     = (const float*)d_in[6];
    const float* b1     = (const float*)d_in[7];
    const float* w2     = (const float*)d_in[8];
    const float* b2     = (const float*)d_in[9];
    float* out = (float*)d_out;
    unsigned short* featT = (unsigned short*)d_ws;   // (V-1, HW, C) f16 = 37.7 MB

    dim3 g(HWn/256, Vn-1);
    transpose_kernel<<<g, 128, 0, stream>>>(feat, featT);
    gbinet_kernel<<<HWn/32, 256, 0, stream>>>(feat, depths, K, E,
                                              w0,b0,w1,b1,w2,b2, featT, out);
}

// Round 9
// 226.720 us; speedup vs baseline: 1.0786x; 1.0786x over previous
//
#include <hip/hip_runtime.h>
#include <math.h>

#define Vn 5
#define Cn 32
#define Hn 384
#define Wn 384
#define Dn 4
#define Gn 8
#define HWn (Hn*Wn)   // 147456

typedef _Float16 h2 __attribute__((ext_vector_type(2)));
typedef float    f2 __attribute__((ext_vector_type(2)));

__device__ __forceinline__ float fdot2h(h2 a, h2 b, float c){
#if __has_builtin(__builtin_amdgcn_fdot2)
    return __builtin_amdgcn_fdot2(a, b, c, false);
#else
    return (float)a.x*(float)b.x + (float)a.y*(float)b.y + c;
#endif
}
__device__ __forceinline__ unsigned int packh2(float a, float b){  // accurate pack (RNE)
    h2 h;
    h.x = (_Float16)a;
    h.y = (_Float16)b;
    return __builtin_bit_cast(unsigned int, h);
}
// packed fp32 helpers -> v_pk_fma_f32 / v_pk_max_f32 (exact same fma math per lane)
__device__ __forceinline__ f2 fma2(f2 a, f2 b, f2 c){ return __builtin_elementwise_fma(a, b, c); }
__device__ __forceinline__ f2 max2(f2 a, f2 b){ return __builtin_elementwise_max(a, b); }
__device__ __forceinline__ f2 splat2(float x){ f2 r; r.x = x; r.y = x; return r; }

// ---------- small 3x3 helpers (device) ----------
__device__ __forceinline__ void inv3(const float* m, float* o){
    float a=m[0],b=m[1],c=m[2],d=m[3],e=m[4],f=m[5],g=m[6],h=m[7],i=m[8];
    float A =  e*i - f*h;
    float B = -(d*i - f*g);
    float C =  d*h - e*g;
    float det = a*A + b*B + c*C;
    float r = 1.f/det;
    o[0] = A*r;            o[1] = -(b*i - c*h)*r;  o[2] =  (b*f - c*e)*r;
    o[3] = B*r;            o[4] =  (a*i - c*g)*r;  o[5] = -(a*f - c*d)*r;
    o[6] = C*r;            o[7] = -(a*h - b*g)*r;  o[8] =  (a*e - b*d)*r;
}
__device__ __forceinline__ void mm3(const float* a, const float* b, float* o){
    #pragma unroll
    for (int r=0;r<3;r++)
        #pragma unroll
        for (int c=0;c<3;c++)
            o[r*3+c] = a[r*3+0]*b[0*3+c] + a[r*3+1]*b[1*3+c] + a[r*3+2]*b[2*3+c];
}
__device__ __forceinline__ void mv3(const float* a, const float* v, float* o){
    #pragma unroll
    for (int r=0;r<3;r++)
        o[r] = a[r*3+0]*v[0] + a[r*3+1]*v[1] + a[r*3+2]*v[2];
}

// ---------- transpose+convert (C,H,W) fp32 -> (H*W, C) f16 ----------
// R7 structure (best): instruction-contiguous loads AND stores via LDS
// exchange; 2 px/thread, 18KB LDS, 2304 blocks. Rest-side accounting across
// R2..R8 shows transpose variants are within run noise; this one is at or
// near its floor and "rest" is dominated by harness reset dispatches.
__global__ __launch_bounds__(128)
void transpose_kernel(const float* __restrict__ feat, unsigned short* __restrict__ featT){
    __shared__ uint4 lds[128*9];                            // 18KB: 8 chunks + 1 pad/thread
    const int s  = blockIdx.y;                              // 0..3 -> view s+1
    const int P0 = blockIdx.x * 256;
    const int t  = threadIdx.x;
    const float* src = feat + (size_t)(s+1)*Cn*HWn + P0 + 2*t;
    unsigned int outw[2][16];
    #pragma unroll
    for (int c=0; c<Cn; c+=2){
        const f2 a = *(const f2*)(src + (size_t)c*HWn);
        const f2 b = *(const f2*)(src + (size_t)(c+1)*HWn);
        outw[0][c>>1] = packh2(a.x, b.x);
        outw[1][c>>1] = packh2(a.y, b.y);
    }
    #pragma unroll
    for (int p=0;p<2;p++)
        #pragma unroll
        for (int j=0;j<4;j++){
            uint4 o;
            o.x = outw[p][4*j+0];
            o.y = outw[p][4*j+1];
            o.z = outw[p][4*j+2];
            o.w = outw[p][4*j+3];
            lds[t*9 + p*4 + j] = o;
        }
    __syncthreads();
    unsigned short* dstb = featT + ((size_t)s*HWn + P0)*Cn;
    #pragma unroll
    for (int k=0;k<8;k++){
        const int c = k*128 + t;
        const uint4 v = lds[(c>>3)*9 + (c&7)];
        *(uint4*)(dstb + (size_t)c*8) = v;
    }
}

// one group (4 ch = 2 half2): two v_dot2_f32_f16 + one fma into sg[g]
#define DOTG(uA, uB, g, WV)                                                    \
    {                                                                          \
        const h2 pa = __builtin_bit_cast(h2, (uA));                            \
        const h2 pb = __builtin_bit_cast(h2, (uB));                            \
        const float dt = fdot2h(pa, r2[2*(g)], fdot2h(pb, r2[2*(g)+1], 0.f));  \
        sg[(g)] = fmaf((WV), dt, sg[(g)]);                                     \
    }

// guarded bilinear tap: loads only if weight nonzero, immediate consume.
// This exact pattern is a measured local optimum. Evidence:
//  R2: batch 16 records/depth  -> VGPR 128, Occ -23pt, 85->129us.
//  R5: quarter-lane coalescing -> +15us shuffle VALU, 78->94us.
//  R8: branchless (~2 records) -> VGPR 56, Occ 43->37%, 78->95.6us,
//      with IDENTICAL absolute VALU time and FETCH_SIZE -> pure scheduling
//      loss. The w!=0 exec-branch pins the scheduler to load->consume with
//      minimal live ranges; wave interleaving (43% Occ) hides the rest.
__device__ __forceinline__ void tap_f16(const unsigned short* __restrict__ vbase,
                                        int xc, int yc, float w,
                                        const h2* r2, float* sg)
{
    if (w != 0.f){
        const uint4* p = (const uint4*)(vbase + ((size_t)yc*Wn + xc)*Cn);
        const uint4 q0 = p[0];
        const uint4 q1 = p[1];
        const uint4 q2 = p[2];
        const uint4 q3 = p[3];
        DOTG(q0.x, q0.y, 0, w)
        DOTG(q0.z, q0.w, 1, w)
        DOTG(q1.x, q1.y, 2, w)
        DOTG(q1.z, q1.w, 3, w)
        DOTG(q2.x, q2.y, 4, w)
        DOTG(q2.z, q2.w, 5, w)
        DOTG(q3.x, q3.y, 6, w)
        DOTG(q3.z, q3.w, 7, w)
    }
}

// ---------- fused main kernel (R4/R7 structure, best measured: 77.4us) ----
// One thread per (pixel, view, depth-half). Block = 256 threads =
// 32 pixels x 8 lanes; lane sub = s*2 + h. Each thread: 2 depths x 4 taps,
// packed-f2 MLP pass, shfl_xor(1) folds depth-half maxlog, shfl_xor(2)/(4)
// view reduction. NOTE: register arrays only with compile-time indices (SROA).
__global__ __launch_bounds__(256, 2)
void gbinet_kernel(const float* __restrict__ feat,
                   const float* __restrict__ depths,
                   const float* __restrict__ Kin,
                   const float* __restrict__ Ein,
                   const float* __restrict__ w0, const float* __restrict__ b0,
                   const float* __restrict__ w1, const float* __restrict__ b1,
                   const float* __restrict__ w2, const float* __restrict__ b2,
                   const unsigned short* __restrict__ featT,
                   float* __restrict__ out)
{
    __shared__ float sW0[128], sW1[128], sB0[16], sB1[8], sW2[8], sB2s[1];
    __shared__ float sM[48];            // per source view: A[9] + c[3]
    __shared__ float sRef[32*33];       // 32 pixels x 32 ref channels (pad 33)
    __shared__ float sDep[4*33];        // 4 depth planes x 32 pixels (pad 33)
    __shared__ float sOut[32*33];       // 32 pixels x 32 outputs (pad 33)
    const int t = threadIdx.x;
    if (t < 128){ sW0[t] = w0[t]; sW1[t] = w1[t]; }
    if (t < 16) sB0[t] = b0[t];
    if (t < 8){ sB1[t] = b1[t]; sW2[t] = w2[t]; }

    // XCD swizzle: round-robin dispatch -> each XCD gets a contiguous
    // 576-block (48-row) strip; featT tap neighborhoods stay in its L2.
    const int bid = blockIdx.x;
    const int sid = (bid & 7) * (HWn/32/8) + (bid >> 3);
    const int blockBase = sid * 32;

    // cooperative coalesced stage of ref (view0 fp32) and depths for 32 pixels
    {
        const float* srcR = feat + blockBase;
        #pragma unroll
        for (int k=0;k<4;k++){
            const int i  = k*256 + t;
            const int c  = i >> 5;
            const int px = i & 31;
            sRef[px*33 + c] = srcR[(size_t)c*HWn + px];
        }
        if (t < 128){
            const int dp = t >> 5;      // 0..3
            const int px = t & 31;
            sDep[dp*33 + px] = depths[(size_t)dp*HWn + blockBase + px];
        }
    }

    // Projection-chain setup, 4-way lane-parallel (one lane per source view).
    if (t < 4){
        float K0inv[9]; inv3(Kin, K0inv);
        float R0[9], t0[3];
        #pragma unroll
        for (int r=0;r<3;r++){
            #pragma unroll
            for (int c=0;c<3;c++) R0[r*3+c] = Ein[r*4+c];
            t0[r] = Ein[r*4+3];
        }
        float R0inv[9]; inv3(R0, R0inv);
        float M0[9]; mm3(R0inv, K0inv, M0);
        float Rt0[3]; mv3(R0inv, t0, Rt0);
        const int sv = t + 1;
        const float* Ks = Kin + sv*9;
        const float* Es = Ein + sv*12;
        float Rs[9], ts[3];
        #pragma unroll
        for (int r=0;r<3;r++){
            #pragma unroll
            for (int c=0;c<3;c++) Rs[r*3+c] = Es[r*4+c];
            ts[r] = Es[r*4+3];
        }
        float T1[9]; mm3(Rs, M0, T1);
        float A[9];  mm3(Ks, T1, A);
        float Rr[3]; mv3(Rs, Rt0, Rr);
        float tv[3] = { ts[0]-Rr[0], ts[1]-Rr[1], ts[2]-Rr[2] };
        float cv[3]; mv3(Ks, tv, cv);
        float* dm = &sM[t*12];
        #pragma unroll
        for (int i=0;i<9;i++) dm[i] = A[i];
        #pragma unroll
        for (int i=0;i<3;i++) dm[9+i] = cv[i];
    }
    if (t == 4) sB2s[0] = b2[0];
    __syncthreads();

    const int pixLocal = t >> 3;        // 0..31
    const int sub      = t & 7;
    const int s        = sub >> 1;      // source view index (0..3 -> view s+1)
    const int hh       = sub & 1;       // depth-half: depths {2h, 2h+1}
    const int pix      = blockBase + pixLocal;
    const float xg = (float)(pix % Wn) + 0.5f;
    const float yg = (float)(pix / Wn) + 0.5f;

    // ref as 16 packed half2 (f16 precision > bf16 for N(0,1) data)
    h2 r2[16];
    #pragma unroll
    for (int k=0;k<16;k++){
        r2[k].x = (_Float16)sRef[pixLocal*33 + 2*k];
        r2[k].y = (_Float16)sRef[pixLocal*33 + 2*k+1];
    }
    float dep[2];
    #pragma unroll
    for (int d=0;d<2;d++) dep[d] = sDep[(2*hh + d)*33 + pixLocal];

    const float* M = &sM[s*12];
    const float bx = M[0]*xg + M[1]*yg + M[2];
    const float by = M[3]*xg + M[4]*yg + M[5];
    const float bz = M[6]*xg + M[7]*yg + M[8];
    const float cx = M[9], cy = M[10], cz = M[11];
    const unsigned short* vbase = featT + (size_t)s*HWn*Cn;

    float sim[Gn][2];
    #pragma unroll
    for (int d=0;d<2;d++){
        const float dd = dep[d];
        const float ux = fmaf(bx, dd, cx);
        const float uy = fmaf(by, dd, cy);
        const float uz = fmaf(bz, dd, cz) + 1e-9f;
        const float rz = 1.f/uz;
        const float px = ux*rz, py = uy*rz;
        const float x0 = floorf(px), y0 = floorf(py);
        const float wx1 = px - x0, wy1 = py - y0;
        const float wx0 = 1.f - wx1, wy0 = 1.f - wy1;
        const bool vx0 = (x0 >= 0.f)     && (x0 <= (float)(Wn-1));
        const bool vx1 = (x0 >= -1.f)    && (x0 <= (float)(Wn-2));
        const bool vy0 = (y0 >= 0.f)     && (y0 <= (float)(Hn-1));
        const bool vy1 = (y0 >= -1.f)    && (y0 <= (float)(Hn-2));
        // fold the 1/4 group-mean into the tap weights
        const float w00 = (vx0&&vy0) ? 0.25f*wx0*wy0 : 0.f;
        const float w10 = (vx1&&vy0) ? 0.25f*wx1*wy0 : 0.f;
        const float w01 = (vx0&&vy1) ? 0.25f*wx0*wy1 : 0.f;
        const float w11 = (vx1&&vy1) ? 0.25f*wx1*wy1 : 0.f;
        // clamped integer coords (always safe to load)
        const int xi0 = (int)fminf(fmaxf(x0,     0.f), (float)(Wn-1));
        const int xi1 = (int)fminf(fmaxf(x0+1.f, 0.f), (float)(Wn-1));
        const int yi0 = (int)fminf(fmaxf(y0,     0.f), (float)(Hn-1));
        const int yi1 = (int)fminf(fmaxf(y0+1.f, 0.f), (float)(Hn-1));

        float sg[Gn];
        #pragma unroll
        for (int g=0; g<Gn; g++) sg[g] = 0.f;
        tap_f16(vbase, xi0, yi0, w00, r2, sg);
        tap_f16(vbase, xi1, yi0, w10, r2, sg);
        tap_f16(vbase, xi0, yi1, w01, r2, sg);
        tap_f16(vbase, xi1, yi1, w11, r2, sg);
        #pragma unroll
        for (int g=0; g<Gn; g++) sim[g][d] = sg[g];
    }

    // pixelwise net on this lane's depth pair via packed fp32
    // (v_pk_fma_f32 / v_pk_max_f32): identical fma chain -> bit-identical.
    // max(sigmoid) == sigmoid(max logit).
    f2 sv[Gn];
    #pragma unroll
    for (int g=0; g<Gn; g++){ sv[g].x = sim[g][0]; sv[g].y = sim[g][1]; }
    f2 hreg[16];
    #pragma unroll
    for (int o=0;o<16;o++){
        f2 a = splat2(sB0[o]);
        #pragma unroll
        for (int g=0; g<Gn; g++)
            a = fma2(splat2(sW0[o*Gn+g]), sv[g], a);
        hreg[o] = max2(a, splat2(0.f));
    }
    f2 lg = splat2(sB2s[0]);
    #pragma unroll
    for (int o=0;o<8;o++){
        f2 a = splat2(sB1[o]);
        #pragma unroll
        for (int i=0;i<16;i++)
            a = fma2(splat2(sW1[o*16+i]), hreg[i], a);
        lg = fma2(splat2(sW2[o]), max2(a, splat2(0.f)), lg);
    }
    float mx = fmaxf(lg.x, lg.y);
    const float maxlog = fmaxf(mx, __shfl_xor(mx, 1));   // fold depth halves
    const float vw = 1.f/(1.f + __expf(-maxlog));

    // scale by vw, butterfly-reduce across the 4 view lanes (bits 1-2)
    float wsum = vw;
    wsum += __shfl_xor(wsum, 2);
    wsum += __shfl_xor(wsum, 4);
    #pragma unroll
    for (int g=0;g<Gn;g++)
        #pragma unroll
        for (int d=0;d<2;d++){
            float v = sim[g][d]*vw;
            v += __shfl_xor(v, 2);
            v += __shfl_xor(v, 4);
            sim[g][d] = v;
        }

    if (s == 0){                        // sub 0 (depths 0,1) and sub 1 (2,3)
        const float invw = 1.f/wsum;
        #pragma unroll
        for (int g=0;g<Gn;g++)
            #pragma unroll
            for (int d=0;d<2;d++)
                sOut[pixLocal*33 + g*Dn + 2*hh + d] = sim[g][d]*invw;
    }
    __syncthreads();

    // coalesced write-out: 32 planes x 32 pixels
    float* oBase = out + blockBase;
    #pragma unroll
    for (int k=0;k<4;k++){
        const int e     = k*256 + t;
        const int plane = e >> 5;
        const int pixel = e & 31;
        oBase[(size_t)plane*HWn + pixel] = sOut[pixel*33 + plane];
    }
}

extern "C" void kernel_launch(void* const* d_in, const int* in_sizes, int n_in,
                              void* d_out, int out_size, void* d_ws, size_t ws_size,
                              hipStream_t stream)
{
    (void)in_sizes; (void)n_in; (void)out_size; (void)ws_size;
    const float* feat   = (const float*)d_in[0];
    const float* depths = (const float*)d_in[1];
    const float* K      = (const float*)d_in[2];
    const float* E      = (const float*)d_in[3];
    const float* w0     = (const float*)d_in[4];
    const float* b0     = (const float*)d_in[5];
    const float* w1     = (const float*)d_in[6];
    const float* b1     = (const float*)d_in[7];
    const float* w2     = (const float*)d_in[8];
    const float* b2     = (const float*)d_in[9];
    float* out = (float*)d_out;
    unsigned short* featT = (unsigned short*)d_ws;   // (V-1, HW, C) f16 = 37.7 MB

    dim3 g(HWn/256, Vn-1);
    transpose_kernel<<<g, 128, 0, stream>>>(feat, featT);
    gbinet_kernel<<<HWn/32, 256, 0, stream>>>(feat, depths, K, E,
                                              w0,b0,w1,b1,w2,b2, featT, out);
}